// Round 7
// baseline (366.651 us; speedup 1.0000x reference)
//
#include <hip/hip_runtime.h>
#include <cstdint>
#include <cstddef>

// B=1024 batches, P=64 patches, C=512 channels. res = X + MLP_patch(X), then LN over C.
#define BB 1024
#define PP 64
#define CC 512
#define MM (BB * PP)            // 65536 flattened (b,p) rows
constexpr float LN_EPS = 1e-5f;

typedef short  s16x8 __attribute__((ext_vector_type(8)));
typedef float  f32x4 __attribute__((ext_vector_type(4)));
typedef unsigned int u32x2 __attribute__((ext_vector_type(2)));

__device__ __forceinline__ unsigned cvt_pk_bf16(float lo, float hi) {
    unsigned r;
    asm("v_cvt_pk_bf16_f32 %0, %1, %2" : "=v"(r) : "v"(lo), "v"(hi));  // RNE on gfx950
    return r;
}
__device__ __forceinline__ unsigned cvt_pk_f16(float lo, float hi) {
    unsigned r;
    asm("v_cvt_pkrtz_f16_f32 %0, %1, %2" : "=v"(r) : "v"(lo), "v"(hi));
    return r;
}
__device__ __forceinline__ float h2f(unsigned short h) {
    float f;
    asm("v_cvt_f32_f16 %0, %1" : "=v"(f) : "v"((unsigned)h));
    return f;
}
__device__ __forceinline__ float bflo(unsigned u) { union { unsigned u; float f; } v; v.u = u << 16;          return v.f; }
__device__ __forceinline__ float bfhi(unsigned u) { union { unsigned u; float f; } v; v.u = u & 0xffff0000u;  return v.f; }

__device__ __forceinline__ s16x8 ldwf(const float* p) {
    float4 a = *(const float4*)p;
    float4 b = *(const float4*)(p + 4);
    union { s16x8 v; unsigned u[4]; } r;
    r.u[0] = cvt_pk_bf16(a.x, a.y);
    r.u[1] = cvt_pk_bf16(a.z, a.w);
    r.u[2] = cvt_pk_bf16(b.x, b.y);
    r.u[3] = cvt_pk_bf16(b.z, b.w);
    return r.v;
}

__device__ __forceinline__ float gelu_t(float t) {
    float sg = 1.5957691216f * (t + 0.044715f * t * t * t);
    return t / (1.0f + __expf(-sg));
}

// =====================================================================================
// R7 k_tr: X[m][c] fp32 -> XT[c][m] bf16. Reads are full-row streams (16-KB contiguous
// per wave-instr); writes are 128-B dense per instr (lane=m, one c-plane per instr).
// LDS: row stride 514 shorts (odd word count) -> write-phase reads conflict-free
// (bank = lane mod 32); staging writes ~4-way (hidden under HBM time).
// =====================================================================================
__global__ __launch_bounds__(1024, 4) void k_tr(
    const float* __restrict__ X, unsigned short* __restrict__ XT)
{
    __shared__ unsigned short S[64 * 514];      // 65792 B
    const int tid = threadIdx.x;
    const int mb  = blockIdx.x;                 // 64-row tile
    const int rg  = tid >> 7;                   // row-in-group 0..7
    const int c0  = (tid & 127) * 4;

    #pragma unroll
    for (int it = 0; it < 8; ++it) {
        const int m = it * 8 + rg;
        float4 v = *(const float4*)(X + (size_t)(mb * 64 + m) * CC + c0);
        unsigned* p = (unsigned*)&S[m * 514 + c0];
        p[0] = cvt_pk_bf16(v.x, v.y);
        p[1] = cvt_pk_bf16(v.z, v.w);
    }
    __syncthreads();

    const int wv = tid >> 6, lane = tid & 63;   // wave covers c = wv*32..wv*32+31
    unsigned short* dst = XT + (size_t)(wv * 32) * MM + mb * 64 + lane;
    #pragma unroll
    for (int j = 0; j < 32; ++j) {
        dst[(size_t)j * MM] = S[lane * 514 + wv * 32 + j];
    }
}

// =====================================================================================
// R7 k_mix: reads XT directly -- NO X staging, NO transpose LDS, NO block barriers.
// 256 thr = 4 waves = 4 channels; each wave fully independent (only a wave-private
// HS round-trip + lgkm drain). Per subtile a wave's xf loads cover a contiguous 2-KB
// chunk of its c-plane; residual re-reads hit the same chunk in L1. RT stored directly
// from the swapped-MFMA acc layout (4 consecutive q per f32x4) in 4-KB runs.
// gid%8 pins all 8 b-tile copies of a c-group to one XCD (weights L2-resident).
// =====================================================================================
template<int HALF>
__global__ __launch_bounds__(256, 3) void k_mix_rt(
    const unsigned short* __restrict__ XT, const float* __restrict__ W1,
    const float* __restrict__ B1, const float* __restrict__ W2,
    const float* __restrict__ B2, void* __restrict__ RTv)
{
    __shared__ __align__(16) unsigned short HS[4][1152];   // wave-private planes

    const int tid  = threadIdx.x;
    const int lane = tid & 63;
    const int wv   = tid >> 6;        // wave -> channel offset (0..3)
    const int lb   = lane & 15;       // acc col: b-index
    const int lq   = lane >> 4;       // k-quad / acc row-quad

    const int gid = blockIdx.x;
    const int cgi = gid & 127;        // c-group (4 ch); XCD = gid%8 = cgi%8
    const int bt  = gid >> 7;         // 0..7 b-tile
    const int c   = cgi * 4 + wv;
    const int b0  = bt * 128;

    // ---- W1/W2 fragments resident for the whole kernel (A-operand) ----
    const float* w1c = W1 + (size_t)c * 4096;
    const float* w2c = W2 + (size_t)c * 4096;
    const int wq = lb * 64 + lq * 8;    // W[c][q=mt*16+lb][p=ks*32+lq*8+j]
    s16x8 w1_0_0 = ldwf(w1c +    0 + wq), w1_0_1 = ldwf(w1c +    0 + wq + 32);
    s16x8 w1_1_0 = ldwf(w1c + 1024 + wq), w1_1_1 = ldwf(w1c + 1024 + wq + 32);
    s16x8 w1_2_0 = ldwf(w1c + 2048 + wq), w1_2_1 = ldwf(w1c + 2048 + wq + 32);
    s16x8 w1_3_0 = ldwf(w1c + 3072 + wq), w1_3_1 = ldwf(w1c + 3072 + wq + 32);
    s16x8 w2_0_0 = ldwf(w2c +    0 + wq), w2_0_1 = ldwf(w2c +    0 + wq + 32);
    s16x8 w2_1_0 = ldwf(w2c + 1024 + wq), w2_1_1 = ldwf(w2c + 1024 + wq + 32);
    s16x8 w2_2_0 = ldwf(w2c + 2048 + wq), w2_2_1 = ldwf(w2c + 2048 + wq + 32);
    s16x8 w2_3_0 = ldwf(w2c + 3072 + wq), w2_3_1 = ldwf(w2c + 3072 + wq + 32);
    // biases in regs (acc rows are q = mt*16 + lq*4 + r)
    const float4 b1_0 = *(const float4*)(B1 + c * 64 +  0 + lq * 4);
    const float4 b1_1 = *(const float4*)(B1 + c * 64 + 16 + lq * 4);
    const float4 b1_2 = *(const float4*)(B1 + c * 64 + 32 + lq * 4);
    const float4 b1_3 = *(const float4*)(B1 + c * 64 + 48 + lq * 4);
    const float4 b2_0 = *(const float4*)(B2 + c * 64 +  0 + lq * 4);
    const float4 b2_1 = *(const float4*)(B2 + c * 64 + 16 + lq * 4);
    const float4 b2_2 = *(const float4*)(B2 + c * 64 + 32 + lq * 4);
    const float4 b2_3 = *(const float4*)(B2 + c * 64 + 48 + lq * 4);

    const unsigned short* xtc = XT + (size_t)c * MM;
    unsigned short*       hp  = &HS[wv][0];

    for (int s = 0; s < 8; ++s) {
        const int bb = b0 + s * 16;
        const unsigned short* xrow = xtc + (size_t)(bb + lb) * 64;

        // ---- fragments + residual words straight from XT (2-KB chunk per wave) ----
        s16x8 xf0 = *(const s16x8*)(xrow +      lq * 8);
        s16x8 xf1 = *(const s16x8*)(xrow + 32 + lq * 8);
        u32x2 xv0 = *(const u32x2*)(xrow +  0 + lq * 4);
        u32x2 xv1 = *(const u32x2*)(xrow + 16 + lq * 4);
        u32x2 xv2 = *(const u32x2*)(xrow + 32 + lq * 4);
        u32x2 xv3 = *(const u32x2*)(xrow + 48 + lq * 4);

        // ---- GEMM1 swapped: acc = W1 x X -> lane (b=lb, q=mt*16+lq*4+r); GELU ----
        #define DO1(mt) { \
            f32x4 a = {b1_##mt.x, b1_##mt.y, b1_##mt.z, b1_##mt.w}; \
            a = __builtin_amdgcn_mfma_f32_16x16x32_bf16(w1_##mt##_0, xf0, a, 0, 0, 0); \
            a = __builtin_amdgcn_mfma_f32_16x16x32_bf16(w1_##mt##_1, xf1, a, 0, 0, 0); \
            u32x2 hpk; \
            hpk[0] = cvt_pk_bf16(gelu_t(a[0]), gelu_t(a[1])); \
            hpk[1] = cvt_pk_bf16(gelu_t(a[2]), gelu_t(a[3])); \
            *(u32x2*)(hp + lb * 72 + mt * 16 + lq * 4) = hpk; }   /* ds_write_b64 */
        DO1(0) DO1(1) DO1(2) DO1(3)
        #undef DO1

        // HS plane is wave-private: drain DS ops; no block barrier anywhere.
        asm volatile("s_waitcnt lgkmcnt(0)" ::: "memory");

        s16x8 hf0 = *(const s16x8*)(hp + lb * 72 +  0 + lq * 8);
        s16x8 hf1 = *(const s16x8*)(hp + lb * 72 + 32 + lq * 8);

        // ---- GEMM2 + bias + residual -> direct store RT[c][(bb+lb)*64 + q] ----
        const size_t rbase = (size_t)c * MM + (size_t)(bb + lb) * 64 + lq * 4;
        #define DO2(mt) { \
            f32x4 a = {b2_##mt.x, b2_##mt.y, b2_##mt.z, b2_##mt.w}; \
            a = __builtin_amdgcn_mfma_f32_16x16x32_bf16(w2_##mt##_0, hf0, a, 0, 0, 0); \
            a = __builtin_amdgcn_mfma_f32_16x16x32_bf16(w2_##mt##_1, hf1, a, 0, 0, 0); \
            a[0] += bflo(xv##mt[0]); a[1] += bfhi(xv##mt[0]); \
            a[2] += bflo(xv##mt[1]); a[3] += bfhi(xv##mt[1]); \
            if constexpr (!HALF) { \
                *(f32x4*)((float*)RTv + rbase + mt * 16) = a; \
            } else { \
                u32x2 hv; \
                hv[0] = cvt_pk_f16(a[0], a[1]); \
                hv[1] = cvt_pk_f16(a[2], a[3]); \
                *(u32x2*)((unsigned short*)RTv + rbase + mt * 16) = hv; \
            } }
        DO2(0) DO2(1) DO2(2) DO2(3)
        #undef DO2
        // HS reuse next iter is ordered by the next lgkm drain (same wave). No barrier.
    }
}

// =====================================================================================
// k_ln: tile [512 c][64 (b,p) cols] from RT (256-B runs per c-plane), LN over c in
// LDS, write OUT rows contiguously. (unchanged from R6)
// =====================================================================================
template<int HALF>
__global__ __launch_bounds__(1024, 4) void k_ln_rt(
    const void* __restrict__ RTv, float* __restrict__ OUT,
    const float* __restrict__ G,  const float* __restrict__ Be)
{
    __shared__ float S[64][516];
    __shared__ float pS[16][64];
    __shared__ float pQ[16][64];
    __shared__ float mu_s[64], inv_s[64];
    __shared__ float gS[512], bS[512];

    const int tid = threadIdx.x;
    const int colbase = blockIdx.x * 64;

    if (tid < 512) gS[tid] = G[tid];
    else           bS[tid - 512] = Be[tid - 512];

    #pragma unroll
    for (int pass = 0; pass < 8; ++pass) {
        const int cc = pass * 64 + (tid >> 4);
        const int ch = (tid & 15) * 4;
        float v0, v1, v2, v3;
        if constexpr (!HALF) {
            f32x4 v = *(const f32x4*)((const float*)RTv + (size_t)cc * MM + colbase + ch);
            v0 = v[0]; v1 = v[1]; v2 = v[2]; v3 = v[3];
        } else {
            u32x2 v = *(const u32x2*)((const unsigned short*)RTv + (size_t)cc * MM + colbase + ch);
            v0 = h2f((unsigned short)(v[0] & 0xffff)); v1 = h2f((unsigned short)(v[0] >> 16));
            v2 = h2f((unsigned short)(v[1] & 0xffff)); v3 = h2f((unsigned short)(v[1] >> 16));
        }
        S[ch + 0][cc] = v0; S[ch + 1][cc] = v1;
        S[ch + 2][cc] = v2; S[ch + 3][cc] = v3;
    }
    __syncthreads();

    const int col = tid >> 4;
    const int cs  = tid & 15;
    float sum = 0.f, sq = 0.f;
    #pragma unroll
    for (int j = 0; j < 32; ++j) {
        float v = S[col][j * 16 + cs];
        sum += v; sq += v * v;
    }
    pS[cs][col] = sum; pQ[cs][col] = sq;
    __syncthreads();

    if (tid < 64) {
        float s = 0.f, q = 0.f;
        #pragma unroll
        for (int k = 0; k < 16; ++k) { s += pS[k][tid]; q += pQ[k][tid]; }
        const float mu  = s * (1.0f / CC);
        const float var = q * (1.0f / CC) - mu * mu;
        mu_s[tid]  = mu;
        inv_s[tid] = rsqrtf(var + LN_EPS);
    }
    __syncthreads();

    const int pos = tid & 7;
    const int hs  = (tid >> 3) & 1;
    const float mu  = mu_s[col];
    const float inv = inv_s[col];
    float* orow = OUT + (size_t)(colbase + col) * CC;
    #pragma unroll
    for (int k = 0; k < 8; ++k) {
        const int cc = hs * 256 + k * 32 + pos * 4;
        f32x4 v = *(const f32x4*)&S[col][cc];
        f32x4 o;
        o[0] = (v[0] - mu) * inv * gS[cc + 0] + bS[cc + 0];
        o[1] = (v[1] - mu) * inv * gS[cc + 1] + bS[cc + 1];
        o[2] = (v[2] - mu) * inv * gS[cc + 2] + bS[cc + 2];
        o[3] = (v[3] - mu) * inv * gS[cc + 3] + bS[cc + 3];
        *(f32x4*)(orow + cc) = o;
    }
}

// =====================================================================================
// Legacy fallback (proven R2/R6 path) if workspace is too small.
// =====================================================================================
__global__ __launch_bounds__(1024) void k_mix_legacy(
    const float* __restrict__ X,  const float* __restrict__ W1,
    const float* __restrict__ B1, const float* __restrict__ W2,
    const float* __restrict__ B2, float* __restrict__ OUT)
{
    __shared__ __align__(16) unsigned short XS[16 * 1160];
    __shared__ __align__(16) unsigned short HS[16 * 1152];
    __shared__ __align__(16) float          RS[16 * 1092];
    __shared__ __align__(16) float          BS[16 * 128];

    const int tid  = threadIdx.x;
    const int lane = tid & 63;
    const int wv   = tid >> 6;
    const int lb   = lane & 15;
    const int lq   = lane >> 4;

    const int gid = blockIdx.x;
    const int cg  = gid & 31;
    const int bt  = gid >> 5;
    const int c0  = cg * 16, b0 = bt * 128;
    const int c   = c0 + wv;

    const float* w1c = W1 + (size_t)c * 4096;
    const float* w2c = W2 + (size_t)c * 4096;
    const int wq = lb * 64 + lq * 8;
    s16x8 w1_0_0 = ldwf(w1c +    0 + wq), w1_0_1 = ldwf(w1c +    0 + wq + 32);
    s16x8 w1_1_0 = ldwf(w1c + 1024 + wq), w1_1_1 = ldwf(w1c + 1024 + wq + 32);
    s16x8 w1_2_0 = ldwf(w1c + 2048 + wq), w1_2_1 = ldwf(w1c + 2048 + wq + 32);
    s16x8 w1_3_0 = ldwf(w1c + 3072 + wq), w1_3_1 = ldwf(w1c + 3072 + wq + 32);
    s16x8 w2_0_0 = ldwf(w2c +    0 + wq), w2_0_1 = ldwf(w2c +    0 + wq + 32);
    s16x8 w2_1_0 = ldwf(w2c + 1024 + wq), w2_1_1 = ldwf(w2c + 1024 + wq + 32);
    s16x8 w2_2_0 = ldwf(w2c + 2048 + wq), w2_2_1 = ldwf(w2c + 2048 + wq + 32);
    s16x8 w2_3_0 = ldwf(w2c + 3072 + wq), w2_3_1 = ldwf(w2c + 3072 + wq + 32);

    BS[wv * 128 +      lane] = B1[c * 64 + lane];
    BS[wv * 128 + 64 + lane] = B2[c * 64 + lane];

    const unsigned short* xp = &XS[wv * 1160];
    unsigned short*       hp = &HS[wv * 1152];

    const int sc4 = tid & 3;
    const int sp2 = (tid >> 2) & 31;
    const int sbo = tid >> 7;

    float4 r0[2], r1[2];
    #pragma unroll
    for (int pass = 0; pass < 2; ++pass) {
        const float* src = X + ((size_t)(b0 + pass * 8 + sbo) * PP + 2 * sp2) * CC
                             + c0 + sc4 * 4;
        r0[pass] = *(const float4*)src;
        r1[pass] = *(const float4*)(src + CC);
    }

    for (int s = 0; s < 8; ++s) {
        const int bb = b0 + s * 16;
        #pragma unroll
        for (int pass = 0; pass < 2; ++pass) {
            int b = pass * 8 + sbo;
            *(unsigned*)&XS[(sc4 * 4 + 0) * 1160 + b * 72 + 2 * sp2] = cvt_pk_bf16(r0[pass].x, r1[pass].x);
            *(unsigned*)&XS[(sc4 * 4 + 1) * 1160 + b * 72 + 2 * sp2] = cvt_pk_bf16(r0[pass].y, r1[pass].y);
            *(unsigned*)&XS[(sc4 * 4 + 2) * 1160 + b * 72 + 2 * sp2] = cvt_pk_bf16(r0[pass].z, r1[pass].z);
            *(unsigned*)&XS[(sc4 * 4 + 3) * 1160 + b * 72 + 2 * sp2] = cvt_pk_bf16(r0[pass].w, r1[pass].w);
        }
        __syncthreads();
        if (s < 7) {
            #pragma unroll
            for (int pass = 0; pass < 2; ++pass) {
                const float* src = X + ((size_t)(bb + 16 + pass * 8 + sbo) * PP + 2 * sp2) * CC
                                     + c0 + sc4 * 4;
                r0[pass] = *(const float4*)src;
                r1[pass] = *(const float4*)(src + CC);
            }
        }
        s16x8 xf0 = *(const s16x8*)(xp + lb * 72 +  0 + lq * 8);
        s16x8 xf1 = *(const s16x8*)(xp + lb * 72 + 32 + lq * 8);
        #define DO1(mt) { \
            float4 bv = *(const float4*)&BS[wv * 128 + mt * 16 + lq * 4]; \
            f32x4 a = {bv.x, bv.y, bv.z, bv.w}; \
            a = __builtin_amdgcn_mfma_f32_16x16x32_bf16(w1_##mt##_0, xf0, a, 0, 0, 0); \
            a = __builtin_amdgcn_mfma_f32_16x16x32_bf16(w1_##mt##_1, xf1, a, 0, 0, 0); \
            u32x2 hpk; \
            hpk[0] = cvt_pk_bf16(gelu_t(a[0]), gelu_t(a[1])); \
            hpk[1] = cvt_pk_bf16(gelu_t(a[2]), gelu_t(a[3])); \
            *(u32x2*)(hp + lb * 72 + mt * 16 + lq * 4) = hpk; }
        DO1(0) DO1(1) DO1(2) DO1(3)
        #undef DO1
        asm volatile("s_waitcnt lgkmcnt(0)" ::: "memory");
        s16x8 hf0 = *(const s16x8*)(hp + lb * 72 +  0 + lq * 8);
        s16x8 hf1 = *(const s16x8*)(hp + lb * 72 + 32 + lq * 8);
        #define DO2(mt) { \
            float4 bv = *(const float4*)&BS[wv * 128 + 64 + mt * 16 + lq * 4]; \
            f32x4 a = {bv.x, bv.y, bv.z, bv.w}; \
            a = __builtin_amdgcn_mfma_f32_16x16x32_bf16(w2_##mt##_0, hf0, a, 0, 0, 0); \
            a = __builtin_amdgcn_mfma_f32_16x16x32_bf16(w2_##mt##_1, hf1, a, 0, 0, 0); \
            u32x2 xv = *(const u32x2*)(xp + lb * 72 + mt * 16 + lq * 4); \
            a[0] += bflo(xv[0]); a[1] += bfhi(xv[0]); \
            a[2] += bflo(xv[1]); a[3] += bfhi(xv[1]); \
            *(f32x4*)&RS[lb * 1092 + wv * 68 + mt * 16 + lq * 4] = a; }
        DO2(0) DO2(1) DO2(2) DO2(3)
        #undef DO2
        __syncthreads();
        #pragma unroll
        for (int it = 0; it < 4; ++it) {
            int fi = it * 1024 + tid;
            int c4 = fi & 3, q = (fi >> 2) & 63, b = fi >> 8;
            const float* rp = &RS[b * 1092 + c4 * 4 * 68 + q];
            float4 v = { rp[0], rp[68], rp[136], rp[204] };
            *(float4*)(OUT + ((size_t)(bb + b) * PP + q) * CC + c0 + c4 * 4) = v;
        }
    }
}

__global__ __launch_bounds__(256) void k_ln_legacy(
    float* __restrict__ OUT, const float* __restrict__ G, const float* __restrict__ Be)
{
    const int lane = threadIdx.x & 63;
    const int m    = blockIdx.x * 4 + (threadIdx.x >> 6);
    float4* row = (float4*)(OUT + (size_t)m * CC);
    float4 v0 = row[lane], v1 = row[lane + 64];
    float s = (v0.x + v0.y) + (v0.z + v0.w) + (v1.x + v1.y) + (v1.z + v1.w);
    float q = (v0.x * v0.x + v0.y * v0.y) + (v0.z * v0.z + v0.w * v0.w)
            + (v1.x * v1.x + v1.y * v1.y) + (v1.z * v1.z + v1.w * v1.w);
    #pragma unroll
    for (int o = 32; o >= 1; o >>= 1) {
        s += __shfl_xor(s, o, 64);
        q += __shfl_xor(q, o, 64);
    }
    const float mu  = s * (1.0f / CC);
    const float var = q * (1.0f / CC) - mu * mu;
    const float inv = rsqrtf(var + LN_EPS);
    const float4 g0 = ((const float4*)G)[lane],  g1 = ((const float4*)G)[lane + 64];
    const float4 e0 = ((const float4*)Be)[lane], e1 = ((const float4*)Be)[lane + 64];
    v0.x = (v0.x - mu) * inv * g0.x + e0.x;  v0.y = (v0.y - mu) * inv * g0.y + e0.y;
    v0.z = (v0.z - mu) * inv * g0.z + e0.z;  v0.w = (v0.w - mu) * inv * g0.w + e0.w;
    v1.x = (v1.x - mu) * inv * g1.x + e1.x;  v1.y = (v1.y - mu) * inv * g1.y + e1.y;
    v1.z = (v1.z - mu) * inv * g1.z + e1.z;  v1.w = (v1.w - mu) * inv * g1.w + e1.w;
    row[lane] = v0; row[lane + 64] = v1;
}

extern "C" void kernel_launch(void* const* d_in, const int* in_sizes, int n_in,
                              void* d_out, int out_size, void* d_ws, size_t ws_size,
                              hipStream_t stream) {
    const float* X  = (const float*)d_in[0];
    const float* W1 = (const float*)d_in[1];
    const float* B1 = (const float*)d_in[2];
    const float* W2 = (const float*)d_in[3];
    const float* B2 = (const float*)d_in[4];
    const float* G  = (const float*)d_in[5];
    const float* Be = (const float*)d_in[6];
    float* OUT = (float*)d_out;

    const size_t xt_bytes = (size_t)CC * MM * sizeof(unsigned short);  //  67 MB
    const size_t rt32     = (size_t)CC * MM * sizeof(float);           // 134 MB
    const size_t rt16     = xt_bytes;                                  //  67 MB

    if (d_ws && ws_size >= xt_bytes + rt32) {
        unsigned short* XT = (unsigned short*)d_ws;
        float* RT = (float*)((char*)d_ws + xt_bytes);
        k_tr<<<MM / 64, 1024, 0, stream>>>(X, XT);
        k_mix_rt<0><<<1024, 256, 0, stream>>>(XT, W1, B1, W2, B2, RT);
        k_ln_rt<0><<<MM / 64, 1024, 0, stream>>>(RT, OUT, G, Be);
    } else if (d_ws && ws_size >= xt_bytes + rt16) {
        unsigned short* XT = (unsigned short*)d_ws;
        unsigned short* RT = (unsigned short*)((char*)d_ws + xt_bytes);
        k_tr<<<MM / 64, 1024, 0, stream>>>(X, XT);
        k_mix_rt<1><<<1024, 256, 0, stream>>>(XT, W1, B1, W2, B2, RT);
        k_ln_rt<1><<<MM / 64, 1024, 0, stream>>>(RT, OUT, G, Be);
    } else {
        k_mix_legacy<<<256, 1024, 0, stream>>>(X, W1, B1, W2, B2, OUT);
        k_ln_legacy<<<MM / 4, 256, 0, stream>>>(OUT, G, Be);
    }
}